// Round 3
// baseline (367.261 us; speedup 1.0000x reference)
//
#include <hip/hip_runtime.h>

// Softmax over 32M fp32: out = exp(x) / sum(exp(x))  (no max-subtraction, per reference)
//
// SINGLE fused dispatch (plain <<<>>> launch — NOT hipLaunchCooperativeKernel, which
// hung the container in R1). Grid-wide handoff via the last-block pattern:
//   Phase 1: grid-stride float4 loads (x4 ILP), per-thread exp-sum, wave64 shuffle
//            reduce, LDS reduce, partial -> partials[blockIdx]; __threadfence;
//            atomicAdd ticket (device-scope by default on gfx950).
//   The LAST-arriving block reduces the 1024 partials and release-stores the total;
//   every block's thread 0 acquire-polls the flag with s_sleep backoff, then
//   broadcasts r = 1/total through LDS.
//   Phase 2: same slice re-read (L3-hot: input 128 MiB < 256 MiB Infinity Cache),
//            exp + scale, non-temporal stores (don't evict the input / pollute L3).
//
// Deadlock safety: the spin requires all blocks co-resident. GRID=1024 = 4 blocks/CU
// with __launch_bounds__(256,4) (VGPR cap 128; kernel needs ~50) = 2x residency
// slack vs the 8/CU hardware max. Dedicated GPU, single stream, no preemption.
//
// Workspace layout (d_ws): [int cnt][int flag][float total][pad][float partials[GRID]]
// cnt+flag (8 bytes) are zeroed per-invocation by an in-stream hipMemsetAsync
// (graph-capturable; d_ws arrives poisoned so sync vars MUST be initialized).

#define BLOCK 256
#define GRID 1024  // 4 blocks/CU: 2x co-residency slack for the spin barrier

typedef float vfloat4 __attribute__((ext_vector_type(4)));

__global__ __launch_bounds__(BLOCK, 4) void softmax_fused(
    const float* __restrict__ inp, float* __restrict__ out,
    int* __restrict__ ws_i, float* __restrict__ ws_f, int n4) {
  int* cnt = ws_i;            // ws bytes [0,4)
  int* flag = ws_i + 1;       // ws bytes [4,8)
  float* total = ws_f + 2;    // ws bytes [8,12)
  float* partials = ws_f + 4; // ws bytes [16, 16+4*GRID)

  const vfloat4* __restrict__ in4 = (const vfloat4*)inp;
  vfloat4* __restrict__ out4 = (vfloat4*)out;
  const int tid = blockIdx.x * BLOCK + threadIdx.x;
  const int stride = GRID * BLOCK;  // 262144 float4 slots

  // ---- Phase 1: exp-sum over this thread's slice (32 float4 / thread) ----
  float s0 = 0.0f, s1 = 0.0f, s2 = 0.0f, s3 = 0.0f;
  int i = tid;
  for (; i + 3 * stride < n4; i += 4 * stride) {
    vfloat4 a = in4[i];
    vfloat4 b = in4[i + stride];
    vfloat4 c = in4[i + 2 * stride];
    vfloat4 d = in4[i + 3 * stride];
    s0 += __expf(a.x) + __expf(a.y) + __expf(a.z) + __expf(a.w);
    s1 += __expf(b.x) + __expf(b.y) + __expf(b.z) + __expf(b.w);
    s2 += __expf(c.x) + __expf(c.y) + __expf(c.z) + __expf(c.w);
    s3 += __expf(d.x) + __expf(d.y) + __expf(d.z) + __expf(d.w);
  }
  for (; i < n4; i += stride) {
    vfloat4 a = in4[i];
    s0 += __expf(a.x) + __expf(a.y) + __expf(a.z) + __expf(a.w);
  }
  float s = (s0 + s1) + (s2 + s3);

  #pragma unroll
  for (int off = 32; off > 0; off >>= 1)
    s += __shfl_down(s, off, 64);

  __shared__ float wsum[BLOCK / 64];
  __shared__ int is_last;
  __shared__ float r_bcast;
  if ((threadIdx.x & 63) == 0) wsum[threadIdx.x >> 6] = s;
  __syncthreads();

  if (threadIdx.x == 0) {
    partials[blockIdx.x] = wsum[0] + wsum[1] + wsum[2] + wsum[3];
    __threadfence();  // publish partial before the ticket
    int old = atomicAdd(cnt, 1);  // device-scope by default on gfx950
    is_last = (old == GRID - 1);
  }
  __syncthreads();

  // ---- Last-arriving block: final reduce of the GRID partials ----
  if (is_last) {
    float t = 0.0f;
    #pragma unroll
    for (int k = 0; k < GRID / BLOCK; ++k)
      t += __hip_atomic_load(&partials[k * BLOCK + threadIdx.x],
                             __ATOMIC_RELAXED, __HIP_MEMORY_SCOPE_AGENT);
    #pragma unroll
    for (int off = 32; off > 0; off >>= 1)
      t += __shfl_down(t, off, 64);
    if ((threadIdx.x & 63) == 0) wsum[threadIdx.x >> 6] = t;
    __syncthreads();
    if (threadIdx.x == 0) {
      *total = wsum[0] + wsum[1] + wsum[2] + wsum[3];
      __hip_atomic_store(flag, 1, __ATOMIC_RELEASE, __HIP_MEMORY_SCOPE_AGENT);
    }
  }

  // ---- All blocks: acquire-poll the flag (thread 0 only, sleep backoff) ----
  if (threadIdx.x == 0) {
    while (__hip_atomic_load(flag, __ATOMIC_ACQUIRE, __HIP_MEMORY_SCOPE_AGENT) == 0)
      __builtin_amdgcn_s_sleep(2);
    float tot = __hip_atomic_load(total, __ATOMIC_RELAXED, __HIP_MEMORY_SCOPE_AGENT);
    r_bcast = 1.0f / tot;
  }
  __syncthreads();
  const float r = r_bcast;

  // ---- Phase 2: same slice (L3-hot), exp + scale, non-temporal stores ----
  i = tid;
  for (; i + 3 * stride < n4; i += 4 * stride) {
    vfloat4 a = in4[i];
    vfloat4 b = in4[i + stride];
    vfloat4 c = in4[i + 2 * stride];
    vfloat4 d = in4[i + 3 * stride];
    vfloat4 oa, ob, oc, od;
    oa.x = __expf(a.x) * r; oa.y = __expf(a.y) * r;
    oa.z = __expf(a.z) * r; oa.w = __expf(a.w) * r;
    ob.x = __expf(b.x) * r; ob.y = __expf(b.y) * r;
    ob.z = __expf(b.z) * r; ob.w = __expf(b.w) * r;
    oc.x = __expf(c.x) * r; oc.y = __expf(c.y) * r;
    oc.z = __expf(c.z) * r; oc.w = __expf(c.w) * r;
    od.x = __expf(d.x) * r; od.y = __expf(d.y) * r;
    od.z = __expf(d.z) * r; od.w = __expf(d.w) * r;
    __builtin_nontemporal_store(oa, &out4[i]);
    __builtin_nontemporal_store(ob, &out4[i + stride]);
    __builtin_nontemporal_store(oc, &out4[i + 2 * stride]);
    __builtin_nontemporal_store(od, &out4[i + 3 * stride]);
  }
  for (; i < n4; i += stride) {
    vfloat4 a = in4[i];
    vfloat4 oa;
    oa.x = __expf(a.x) * r; oa.y = __expf(a.y) * r;
    oa.z = __expf(a.z) * r; oa.w = __expf(a.w) * r;
    __builtin_nontemporal_store(oa, &out4[i]);
  }
}

extern "C" void kernel_launch(void* const* d_in, const int* in_sizes, int n_in,
                              void* d_out, int out_size, void* d_ws, size_t ws_size,
                              hipStream_t stream) {
  const float* inp = (const float*)d_in[0];
  float* out = (float*)d_out;
  int n = in_sizes[0];
  int n4 = n >> 2;  // N = 2^25, divisible by 4

  // d_ws arrives poisoned: zero the 8 bytes holding {cnt, flag}.
  hipMemsetAsync(d_ws, 0, 8, stream);
  softmax_fused<<<GRID, BLOCK, 0, stream>>>(inp, out, (int*)d_ws, (float*)d_ws, n4);
}